// Round 2
// baseline (881.806 us; speedup 1.0000x reference)
//
#include <hip/hip_runtime.h>
#include <stdint.h>

// GraphECL loss on MI355X. N=10000, E=330000, IN=512, HID=OUT=256.
// TEMP=0.5, LAM=1e-3, LAMBDA_LOSS=1, BN_EPS=1e-5.

#define TEMP_INV 2.0f
#define LAMC 1.0e-3f
// sqrt(log2(e)/TEMP): folded into bf16 z/q so MFMA acc == exp2 argument
#define SSCALE 1.6986436f

typedef __attribute__((ext_vector_type(8))) __bf16 bf16x8;
typedef __attribute__((ext_vector_type(4))) float f32x4;

__device__ __forceinline__ unsigned short f2bf(float x) {
  union { float f; unsigned int u; } v; v.f = x;
  unsigned int r = v.u + 0x7FFFu + ((v.u >> 16) & 1u);
  return (unsigned short)(r >> 16);
}

__device__ __forceinline__ void g2lds16(const void* gc, void* l) {
  void* g = const_cast<void*>(gc);
  __builtin_amdgcn_global_load_lds(
      (__attribute__((address_space(1))) void*)g,
      (__attribute__((address_space(3))) void*)l, 16, 0, 0);
}

// ---------------- degrees ----------------
__global__ void k_deg(const int* __restrict__ src, const int* __restrict__ dst,
                      float* deg_out, float* deg_in, int E) {
  int i = blockIdx.x * blockDim.x + threadIdx.x;
  if (i < E) {
    atomicAdd(&deg_out[src[i]], 1.0f);
    atomicAdd(&deg_in[dst[i]], 1.0f);
  }
}

__global__ void k_rdeg(const float* __restrict__ deg_out, const float* __restrict__ deg_in,
                       float* rdo, float* rdi, float* idi, int N) {
  int i = blockIdx.x * blockDim.x + threadIdx.x;
  if (i < N) {
    float o = deg_out[i], d = deg_in[i];
    rdo[i] = rsqrtf(o);
    rdi[i] = rsqrtf(d);
    idi[i] = 1.0f / d;  // self loops guarantee d >= 1
  }
}

// exclusive prefix sum of deg_in (ints stored as exact floats); 1 block, 1024 thr
__global__ void k_scan(const float* __restrict__ deg, int* __restrict__ off, int N, int E) {
  __shared__ int sm[1024];
  int tid = threadIdx.x;
  int chunk = (N + 1023) / 1024;
  int b = tid * chunk;
  int sum = 0;
  for (int j = 0; j < chunk; j++) { int i = b + j; if (i < N) sum += (int)deg[i]; }
  sm[tid] = sum;
  __syncthreads();
  for (int s = 1; s < 1024; s <<= 1) {
    int v = (tid >= s) ? sm[tid - s] : 0;
    __syncthreads();
    sm[tid] += v;
    __syncthreads();
  }
  int run = (tid == 0) ? 0 : sm[tid - 1];
  for (int j = 0; j < chunk; j++) {
    int i = b + j;
    if (i < N) { off[i] = run; run += (int)deg[i]; }
  }
  if (tid == 0) off[N] = E;
}

__global__ void k_fill(const int* __restrict__ src, const int* __restrict__ dst,
                       const int* __restrict__ off, int* cur,
                       const float* __restrict__ rdo, const float* __restrict__ rdi,
                       int* adj, float* aw, int E) {
  int e = blockIdx.x * blockDim.x + threadIdx.x;
  if (e < E) {
    int u = src[e], v = dst[e];
    int slot = off[v] + atomicAdd(&cur[v], 1);
    adj[slot] = u;
    aw[slot] = rdo[u] * rdi[v];  // symmetric GCN norm per edge
  }
}

// ---------------- fp32 GEMM: C[M,256] = A[M,K] @ W[K,256] (+bias) ----------------
// 64-row tile, 256 thr, thread = 4 rows x 16 cols (cols 64t+4cg: Wl reads 2-way
// bank-free). At stride 68 floats keeps ds_read_b128 16B-aligned. In-place
// (C==A) safe: each block reads only its own 64 A-rows, stores at the very end.
template <int K, bool BIAS>
__global__ __launch_bounds__(256, 2) void k_gemm(const float* A, const float* __restrict__ W,
                                                 const float* __restrict__ bias, float* C, int M) {
  __shared__ float At[32][68];   // transposed A tile (stride 68: aligned + low conflict)
  __shared__ float Wl[32][256];
  int tid = threadIdx.x;
  int rg = tid >> 4, cg = tid & 15;
  int r0 = rg * 4, cb = cg * 4;
  int row0 = blockIdx.x * 64;
  float acc[4][16] = {};
  for (int k0 = 0; k0 < K; k0 += 32) {
    __syncthreads();
#pragma unroll
    for (int t = 0; t < 2; t++) {
      int lin = tid + 256 * t;            // 0..511
      int r = lin >> 3, k4 = (lin & 7) * 4;
      int ar = row0 + r; if (ar >= M) ar = M - 1;   // tail clamp (rows discarded)
      float4 a4 = *(const float4*)(A + (size_t)ar * K + k0 + k4);
      At[k4 + 0][r] = a4.x; At[k4 + 1][r] = a4.y;
      At[k4 + 2][r] = a4.z; At[k4 + 3][r] = a4.w;
    }
#pragma unroll
    for (int t = 0; t < 8; t++) {
      int lin = tid + 256 * t;            // 0..2047
      int kk = lin >> 6, c4 = (lin & 63) * 4;
      *(float4*)&Wl[kk][c4] = *(const float4*)(W + (size_t)(k0 + kk) * 256 + c4);
    }
    __syncthreads();
#pragma unroll
    for (int k = 0; k < 32; k++) {
      float4 a4 = *(const float4*)&At[k][r0];   // aligned (272B row stride), bcast
      float av[4] = {a4.x, a4.y, a4.z, a4.w};
#pragma unroll
      for (int t = 0; t < 4; t++) {
        float4 w4 = *(const float4*)&Wl[k][64 * t + cb];   // block 16t+cg: 2-way free
#pragma unroll
        for (int i = 0; i < 4; i++) {
          acc[i][4 * t + 0] += av[i] * w4.x;
          acc[i][4 * t + 1] += av[i] * w4.y;
          acc[i][4 * t + 2] += av[i] * w4.z;
          acc[i][4 * t + 3] += av[i] * w4.w;
        }
      }
    }
  }
#pragma unroll
  for (int i = 0; i < 4; i++) {
    int r = row0 + r0 + i;
    if (r < M) {
      float* crow = C + (size_t)r * 256;
#pragma unroll
      for (int t = 0; t < 4; t++) {
        int c = 64 * t + cb;
        float4 v = {acc[i][4 * t], acc[i][4 * t + 1], acc[i][4 * t + 2], acc[i][4 * t + 3]};
        if constexpr (BIAS) {
          float4 b4 = *(const float4*)(bias + c);
          v.x += b4.x; v.y += b4.y; v.z += b4.z; v.w += b4.w;
        }
        *(float4*)(crow + c) = v;
      }
    }
  }
}

// ---------------- BatchNorm (train) stats + apply + relu ----------------
__global__ void k_bnstat(const float* __restrict__ T, float* s, float* ss, int M) {
  int c = threadIdx.x;
  int r0 = blockIdx.x * 64;
  float a = 0, b = 0;
  for (int r = r0; r < r0 + 64 && r < M; r++) {
    float v = T[(size_t)r * 256 + c];
    a += v; b += v * v;
  }
  atomicAdd(&s[c], a);
  atomicAdd(&ss[c], b);
}

__global__ void k_bnrelu(float* T, const float* __restrict__ s, const float* __restrict__ ss,
                         const float* __restrict__ g, const float* __restrict__ b, int M) {
  int r = blockIdx.x, c = threadIdx.x;
  float invM = 1.0f / (float)M;
  float mu = s[c] * invM;
  float var = ss[c] * invM - mu * mu;   // biased var, matches jnp.var
  float w = rsqrtf(var + 1e-5f) * g[c];
  float v = T[(size_t)r * 256 + c];
  v = (v - mu) * w + b[c];
  T[(size_t)r * 256 + c] = fmaxf(v, 0.0f);
}

// ---------------- CSR gather-aggregate: Y[v] = sum_{in-edges} w * X[src] (+bias)(relu) ---------
template <bool UNIT, bool RELU>
__global__ __launch_bounds__(256) void k_agg(const float* __restrict__ X, const int* __restrict__ off,
                                             const int* __restrict__ adj, const float* __restrict__ w,
                                             const float* __restrict__ bias, float* __restrict__ Y, int N) {
  int wv = threadIdx.x >> 6, ln = threadIdx.x & 63;
  int v = blockIdx.x * 4 + wv;
  if (v >= N) return;
  int s0 = off[v], s1 = off[v + 1];
  const float4* X4 = (const float4*)X;
  float4 acc = {0, 0, 0, 0};
  for (int s = s0; s < s1; s++) {
    int u = adj[s];
    float wt = UNIT ? 1.0f : w[s];
    float4 x = X4[(size_t)u * 64 + ln];
    acc.x += wt * x.x; acc.y += wt * x.y; acc.z += wt * x.z; acc.w += wt * x.w;
  }
  if constexpr (!UNIT) {
    float4 b = ((const float4*)bias)[ln];
    acc.x += b.x; acc.y += b.y; acc.z += b.z; acc.w += b.w;
  }
  if constexpr (RELU) {
    acc.x = fmaxf(acc.x, 0.f); acc.y = fmaxf(acc.y, 0.f);
    acc.z = fmaxf(acc.z, 0.f); acc.w = fmaxf(acc.w, 0.f);
  }
  ((float4*)Y)[(size_t)v * 64 + ln] = acc;
}

// ---------------- row L2-normalize (in place) + scaled bf16 copy; zero pad rows -----------
__global__ __launch_bounds__(256) void k_norm(float* X, unsigned short* Xb, int N, int NPAD) {
  int wv = threadIdx.x >> 6, ln = threadIdx.x & 63;
  int r = blockIdx.x * 4 + wv;
  if (r >= NPAD) return;
  if (r >= N) {  // exact zeros -> each pad j-row adds exp2(0)=1, corrected in k_final
    ushort4 z = {0, 0, 0, 0};
    ((ushort4*)Xb)[(size_t)r * 64 + ln] = z;
    return;
  }
  float4 x = ((const float4*)X)[(size_t)r * 64 + ln];
  float ss = x.x * x.x + x.y * x.y + x.z * x.z + x.w * x.w;
#pragma unroll
  for (int m = 1; m < 64; m <<= 1) ss += __shfl_xor(ss, m, 64);
  float sc = 1.0f / fmaxf(sqrtf(ss), 1e-12f);
  float4 xn = {x.x * sc, x.y * sc, x.z * sc, x.w * sc};
  ((float4*)X)[(size_t)r * 64 + ln] = xn;
  float bs = sc * SSCALE;
  ushort4 b;
  b.x = f2bf(x.x * bs); b.y = f2bf(x.y * bs);
  b.z = f2bf(x.z * bs); b.w = f2bf(x.w * bs);
  ((ushort4*)Xb)[(size_t)r * 64 + ln] = b;
}

// ---------------- similarity row-sums: S1[i]=sum_j exp(z_i.z_j/T), S2[i]=sum_j exp(z_i.q_j/T) ---
// Zb/Qb prescaled by SSCALE so MFMA acc is the exp2 argument directly.
// 128 i-rows/block (A-frags register-resident), 64-row j-tiles of Z and Q in LDS (64KB).
// XOR swizzle byte^=((row&7)<<4): applied to the GLOBAL source (linear LDS dest,
// global_load_lds writes base+lane*16) and to the ds_read address — same involution.
__global__ __launch_bounds__(256, 2) void k_sim(const unsigned short* __restrict__ Zb,
                                                const unsigned short* __restrict__ Qb,
                                                float* __restrict__ S1, float* __restrict__ S2,
                                                int N, int JT, int JS) {
  __shared__ __align__(1024) char LB[65536];
  const int tid = threadIdx.x;
  const int wv = tid >> 6, ln = tid & 63;
  const int i0 = blockIdx.x * 128;

  // stage this block's 128 A-rows of Zb into LDS (rows 0..127)
#pragma unroll
  for (int it = 0; it < 16; it++) {
    int c = it * 4 + wv;                  // 1KB chunk = 2 rows
    int L = c * 1024 + ln * 16;
    int r = L >> 9;
    int o = (L & 511) ^ ((r & 7) << 4);
    g2lds16((const char*)Zb + (size_t)(i0 + r) * 512 + o, (char*)LB + c * 1024);
  }
  __syncthreads();

  // A fragments: wave owns 32 rows (2 rowfrags), full K=256 in registers
  bf16x8 af[2][8];
#pragma unroll
  for (int rf = 0; rf < 2; rf++) {
    int lrow = wv * 32 + rf * 16 + (ln & 15);
#pragma unroll
    for (int kk = 0; kk < 8; kk++) {
      int o = (kk * 64 + ((ln >> 4) << 4)) ^ ((lrow & 7) << 4);
      af[rf][kk] = *(const bf16x8*)(LB + lrow * 512 + o);
    }
  }

  f32x4 rs[2][2] = {};  // row-sum accumulators [rowfrag][mat]

  int jt0 = (blockIdx.y * JT) / JS;
  int jt1 = ((blockIdx.y + 1) * JT) / JS;
  for (int jt = jt0; jt < jt1; jt++) {
    int j0 = jt * 64;
    __syncthreads();  // previous tile fully consumed (incl. af reads on iter 0)
#pragma unroll
    for (int it = 0; it < 16; it++) {
      int c = it * 4 + wv;
      int L = c * 1024 + ln * 16;
      int r = L >> 9;                     // 0..63 = Z tile, 64..127 = Q tile
      int o = (L & 511) ^ ((r & 7) << 4);
      const char* base = (r < 64) ? (const char*)Zb + (size_t)(j0 + r) * 512
                                  : (const char*)Qb + (size_t)(j0 + r - 64) * 512;
      g2lds16(base + o, (char*)LB + c * 1024);
    }
    __syncthreads();  // compiler drains vmcnt before barrier

    f32x4 accZ[2][4] = {};
    f32x4 accQ[2][4] = {};
#pragma unroll
    for (int cf = 0; cf < 4; cf++) {
      int brow = cf * 16 + (ln & 15);
#pragma unroll
      for (int kk = 0; kk < 8; kk++) {
        int o = (kk * 64 + ((ln >> 4) << 4)) ^ ((brow & 7) << 4);
        bf16x8 bz = *(const bf16x8*)(LB + brow * 512 + o);
        bf16x8 bq = *(const bf16x8*)(LB + (brow + 64) * 512 + o);
        accZ[0][cf] = __builtin_amdgcn_mfma_f32_16x16x32_bf16(af[0][kk], bz, accZ[0][cf], 0, 0, 0);
        accZ[1][cf] = __builtin_amdgcn_mfma_f32_16x16x32_bf16(af[1][kk], bz, accZ[1][cf], 0, 0, 0);
        accQ[0][cf] = __builtin_amdgcn_mfma_f32_16x16x32_bf16(af[0][kk], bq, accQ[0][cf], 0, 0, 0);
        accQ[1][cf] = __builtin_amdgcn_mfma_f32_16x16x32_bf16(af[1][kk], bq, accQ[1][cf], 0, 0, 0);
      }
    }
    // epilogue: exp2 and accumulate per-lane row sums
#pragma unroll
    for (int rf = 0; rf < 2; rf++)
#pragma unroll
      for (int cf = 0; cf < 4; cf++)
#pragma unroll
        for (int i = 0; i < 4; i++) {
          rs[rf][0][i] += exp2f(accZ[rf][cf][i]);
          rs[rf][1][i] += exp2f(accQ[rf][cf][i]);
        }
  }

  // reduce the 16 lanes (same l>>4 group) that share each output row; C/D row = (l>>4)*4+reg
#pragma unroll
  for (int rf = 0; rf < 2; rf++)
#pragma unroll
    for (int m = 0; m < 2; m++)
#pragma unroll
      for (int i = 0; i < 4; i++) {
        float v = rs[rf][m][i];
        v += __shfl_xor(v, 1, 64);
        v += __shfl_xor(v, 2, 64);
        v += __shfl_xor(v, 4, 64);
        v += __shfl_xor(v, 8, 64);
        if ((ln & 15) == 0) {
          int row = i0 + wv * 32 + rf * 16 + ((ln >> 4) << 2) + i;
          if (row < N) atomicAdd(((m == 0) ? S1 : S2) + row, v);
        }
      }
}

// ---------------- final loss ----------------
__global__ __launch_bounds__(256) void k_final(const float* __restrict__ zsum, const float* __restrict__ q,
                                               const float* __restrict__ S1, const float* __restrict__ S2,
                                               const int* __restrict__ off, const int* __restrict__ adj,
                                               const float* __restrict__ idi, float* __restrict__ out,
                                               int N, float pad) {
  int wv = threadIdx.x >> 6, ln = threadIdx.x & 63;
  int v = blockIdx.x * 4 + wv;
  if (v >= N) return;
  float4 zs = ((const float4*)zsum)[(size_t)v * 64 + ln];
  float4 qv = ((const float4*)q)[(size_t)v * 64 + ln];
  float d = zs.x * qv.x + zs.y * qv.y + zs.z * qv.z + zs.w * qv.w;
  float s1v = S1[v] - pad;  // remove pad-row exp2(0)=1 contributions
  float lg = 0.0f;
  int e0 = off[v], e1 = off[v + 1];
  for (int s = e0 + ln; s < e1; s += 64) {
    int u = adj[s];
    lg += logf(s1v + LAMC * (S2[u] - pad));
  }
#pragma unroll
  for (int m = 1; m < 64; m <<= 1) {
    d += __shfl_xor(d, m, 64);
    lg += __shfl_xor(lg, m, 64);
  }
  if (ln == 0) {
    float inv = idi[v];
    float posv = d * inv * TEMP_INV;
    float negv = lg * inv;
    atomicAdd(out, (negv - posv) * (1.0f / (float)N));
  }
}

// ---------------- host ----------------
extern "C" void kernel_launch(void* const* d_in, const int* in_sizes, int n_in,
                              void* d_out, int out_size, void* d_ws, size_t ws_size,
                              hipStream_t stream) {
  const float* feat  = (const float*)d_in[0];
  const float* W1    = (const float*)d_in[1];
  const float* b1    = (const float*)d_in[2];
  const float* W2    = (const float*)d_in[3];
  const float* b2    = (const float*)d_in[4];
  const float* Wt1   = (const float*)d_in[5];
  const float* bt1   = (const float*)d_in[6];
  const float* gamma = (const float*)d_in[7];
  const float* beta  = (const float*)d_in[8];
  const float* Wt2   = (const float*)d_in[9];
  const float* bt2   = (const float*)d_in[10];
  const float* Wp    = (const float*)d_in[11];
  const float* bp    = (const float*)d_in[12];
  const int*   src   = (const int*)d_in[13];
  const int*   dst   = (const int*)d_in[14];
  const int N = in_sizes[0] / 512;
  const int E = in_sizes[13];
  const int NTI = (N + 127) / 128, NPAD = NTI * 128, JT = NPAD / 64;
  const int JS = 13;  // j-splits: 79*13=1027 blocks ~= 2 rounds at 2 blocks/CU
  const float PADF = (float)(NPAD - N);

  char* p = (char*)d_ws;
  auto alloc = [&](size_t bytes) { char* r = p; p += (bytes + 255) & ~(size_t)255; return r; };
  float* B0 = (float*)alloc((size_t)N * 256 * 4);            // xw1 -> xw2 -> zsum
  float* B1 = (float*)alloc((size_t)N * 256 * 4);            // t -> tr -> trans -> p -> q
  float* B2 = (float*)alloc((size_t)N * 256 * 4);            // h1 -> h2 -> z
  unsigned short* zb = (unsigned short*)alloc((size_t)NPAD * 256 * 2);
  unsigned short* qb = (unsigned short*)alloc((size_t)NPAD * 256 * 2);
  int*   off = (int*)alloc((size_t)(N + 1) * 4);
  int*   adj = (int*)alloc((size_t)E * 4);
  float* aw  = (float*)alloc((size_t)E * 4);
  char*  zblk = p;                                           // region zeroed each launch
  float* deg_out = (float*)alloc((size_t)N * 4);
  float* deg_in  = (float*)alloc((size_t)N * 4);
  int*   cur     = (int*)alloc((size_t)N * 4);
  float* S1 = (float*)alloc((size_t)N * 4);
  float* S2 = (float*)alloc((size_t)N * 4);
  float* bns  = (float*)alloc(256 * 4);
  float* bnss = (float*)alloc(256 * 4);
  size_t zbytes = (size_t)(p - zblk);
  float* rdo = (float*)alloc((size_t)N * 4);
  float* rdi = (float*)alloc((size_t)N * 4);
  float* idi = (float*)alloc((size_t)N * 4);
  (void)ws_size; (void)n_in; (void)out_size;

  hipMemsetAsync(zblk, 0, zbytes, stream);
  hipMemsetAsync(d_out, 0, 4, stream);

  int gE = (E + 255) / 256, gN = (N + 255) / 256, gb = (N + 63) / 64, gw = (N + 3) / 4;
  k_deg<<<gE, 256, 0, stream>>>(src, dst, deg_out, deg_in, E);
  k_rdeg<<<gN, 256, 0, stream>>>(deg_out, deg_in, rdo, rdi, idi, N);
  k_scan<<<1, 1024, 0, stream>>>(deg_in, off, N, E);
  k_fill<<<gE, 256, 0, stream>>>(src, dst, off, cur, rdo, rdi, adj, aw, E);

  k_gemm<512, false><<<gb, 256, 0, stream>>>(feat, W1, nullptr, B0, N);    // xw1
  k_gemm<512, true ><<<gb, 256, 0, stream>>>(feat, Wt1, bt1, B1, N);       // t
  k_bnstat<<<(N + 63) / 64, 256, 0, stream>>>(B1, bns, bnss, N);
  k_bnrelu<<<N, 256, 0, stream>>>(B1, bns, bnss, gamma, beta, N);          // tr (in place)
  k_gemm<256, true ><<<gb, 256, 0, stream>>>(B1, Wt2, bt2, B1, N);         // trans (in place)
  k_gemm<256, true ><<<gb, 256, 0, stream>>>(B1, Wp, bp, B1, N);           // p (in place)

  k_agg<false, true ><<<gw, 256, 0, stream>>>(B0, off, adj, aw, b1, B2, N);  // h1
  k_gemm<256, false><<<gb, 256, 0, stream>>>(B2, W2, nullptr, B0, N);        // xw2
  k_agg<false, false><<<gw, 256, 0, stream>>>(B0, off, adj, aw, b2, B2, N);  // h2

  int gnp = (NPAD + 3) / 4;
  k_norm<<<gnp, 256, 0, stream>>>(B2, zb, N, NPAD);  // z (in place) + zb
  k_norm<<<gnp, 256, 0, stream>>>(B1, qb, N, NPAD);  // q (in place) + qb

  dim3 gs(NTI, JS);
  k_sim<<<gs, 256, 0, stream>>>(zb, qb, S1, S2, N, JT, JS);

  k_agg<true, false><<<gw, 256, 0, stream>>>(B2, off, adj, aw, nullptr, B0, N);  // zsum
  k_final<<<gw, 256, 0, stream>>>(B0, B1, S1, S2, off, adj, idi, (float*)d_out, N, PADF);
}